// Round 12
// baseline (339.744 us; speedup 1.0000x reference)
//
#include <hip/hip_runtime.h>
#include <math.h>
#include <stdint.h>

#define D 256
#define N 32768
#define M 4096

// output layout (floats): quantized | loss | indices | perplexity
#define LOSS_OFF 8388608
#define IDX_OFF  8388609
#define PERP_OFF 8421377

typedef _Float16 f16;
typedef _Float16 f16x8 __attribute__((ext_vector_type(8)));
typedef _Float16 f16x4 __attribute__((ext_vector_type(4)));
typedef float f32x4 __attribute__((ext_vector_type(4)));

// ---------- workspace layout (bytes), fp16-MFMA path ----------
#define WS_XH     0u          // unused in main path (kept for fallback layout stability)
#define WS_XL     16777216u
#define WS_EH     33554432u
#define WS_EL     35651584u
#define WS_ENORM  37748736u
#define WS_COUNTS 37765120u
#define WS_IDX    37781504u
#define WS_CAND   37912576u   // float2[4][32768]
#define WS_LPART  38961152u
#define WS_NPART  38969344u
#define WS_NEEDED 38977536u
#define C_BLOCKS  2048

__device__ __forceinline__ void gload16(const void* g, void* l) {
    __builtin_amdgcn_global_load_lds(
        (const __attribute__((address_space(1))) uint32_t*)g,
        (__attribute__((address_space(3))) uint32_t*)l, 16, 0, 0);
}

#define MFMA16(a, b, c) __builtin_amdgcn_mfma_f32_16x16x32_f16((a), (b), (c), 0, 0, 0)

// ---------------- K1: embedding norms + zero counts ----------------
__global__ __launch_bounds__(256) void init_kernel(const float* __restrict__ emb,
                                                   float* __restrict__ enorm,
                                                   unsigned* __restrict__ counts) {
    int tid = threadIdx.x;
    int lane = tid & 63;
    int wid = tid >> 6;
    int m = blockIdx.x * 4 + wid;
    const float4* e4 = (const float4*)(emb + (size_t)m * D);
    float4 v = e4[lane];
    float s = v.x * v.x + v.y * v.y + v.z * v.z + v.w * v.w;
    #pragma unroll
    for (int off = 32; off; off >>= 1) s += __shfl_xor(s, off);
    if (lane == 0) enorm[m] = s;
    int gid = blockIdx.x * 256 + tid;
    if (gid < M) counts[gid] = 0u;
}

// ---------------- convert: f32 -> (hi fp16, lo fp16) ----------------
__global__ __launch_bounds__(256) void convert_kernel(const float* __restrict__ s,
                                                      f16* __restrict__ dh,
                                                      f16* __restrict__ dl, int n4) {
    int i = blockIdx.x * 256 + threadIdx.x;
    if (i >= n4) return;
    float4 v = ((const float4*)s)[i];
    f16 h0 = (f16)v.x, h1 = (f16)v.y, h2 = (f16)v.z, h3 = (f16)v.w;
    f16 l0 = (f16)(v.x - (float)h0), l1 = (f16)(v.y - (float)h1);
    f16 l2 = (f16)(v.z - (float)h2), l3 = (f16)(v.w - (float)h3);
    f16x4 hv; hv[0] = h0; hv[1] = h1; hv[2] = h2; hv[3] = h3;
    f16x4 lv; lv[0] = l0; lv[1] = l1; lv[2] = l2; lv[3] = l3;
    *(f16x4*)(dh + (size_t)i * 4) = hv;
    *(f16x4*)(dl + (size_t)i * 4) = lv;
}

// ---------------- K2 (MFMA, A-in-regs): distance argmin ----------------
// x.e ~= xh.eh + xh.el + xl.eh. Per block (128 rows x 1024 cols):
//   A (xh,xl) in VGPRs, converted in-kernel from f32 x (no convert_x pass).
//   E double-buffered in LDS: [2 buf][2 dtype][128 row][128 k] f16 = 2x64KB,
//   slot-XOR swizzled (pre-swizzled global source + swizzled read, rule #21).
// 16 phases = 8 ct x 2 K-half; per phase/wave: 8 gload16 + 32 ds_read_b128 + 96 MFMA,
// one __syncthreads(). 8 waves (512 thr): wr=wid>>1 row-strip, wc=wid&1 col-strip.
__global__ __launch_bounds__(512, 2) void argmin_xr(
    const float* __restrict__ x, const f16* __restrict__ eh,
    const f16* __restrict__ el, const float* __restrict__ enorm,
    float2* __restrict__ cand)
{
    extern __shared__ char smem[];
    float2 (*msm)[32] = (float2(*)[32])smem;   // alias, epilogue only

    int tid = threadIdx.x;
    int lane = tid & 63;
    int wid = tid >> 6;          // 0..7
    int wr = wid >> 1;           // 0..3
    int wc = wid & 1;            // 0..1
    int b = blockIdx.x;
    int rb = (b & 7) * 32 + (b >> 5);   // XCD-grouped: 4 cs of one rb -> same XCD
    int cs = (b >> 3) & 3;
    int row0 = rb * 128;
    int rxor = lane & 7;

    // ---- prologue: stage E phase-0 (ct=0, kh=0) into buf0 ----
    {
        #pragma unroll
        for (int q = 0; q < 8; ++q) {
            int cb = q * 8 + wid;                       // 0..63
            int row = (cb * 4 + (lane >> 4)) & 127;
            int ks = ((lane & 15) ^ (row & 7)) * 8;     // kh=0
            const f16* src = (cb >> 5) ? el : eh;
            gload16(src + (size_t)(cs * 1024 + row) * D + ks, smem + cb * 1024);
        }
    }
    // ---- A regs: load f32 x, split to xh/xl in-kernel (static idx, rule #20) ----
    f16x8 xhr[2][8], xlr[2][8];
    #pragma unroll
    for (int i = 0; i < 2; ++i) {
        const float* xr = x + (size_t)(row0 + wr * 32 + i * 16 + (lane & 15)) * D;
        #pragma unroll
        for (int kc = 0; kc < 8; ++kc) {
            float4 v0 = *(const float4*)(xr + kc * 32 + (lane >> 4) * 8);
            float4 v1 = *(const float4*)(xr + kc * 32 + (lane >> 4) * 8 + 4);
            f16x8 h, l;
            h[0] = (f16)v0.x; l[0] = (f16)(v0.x - (float)h[0]);
            h[1] = (f16)v0.y; l[1] = (f16)(v0.y - (float)h[1]);
            h[2] = (f16)v0.z; l[2] = (f16)(v0.z - (float)h[2]);
            h[3] = (f16)v0.w; l[3] = (f16)(v0.w - (float)h[3]);
            h[4] = (f16)v1.x; l[4] = (f16)(v1.x - (float)h[4]);
            h[5] = (f16)v1.y; l[5] = (f16)(v1.y - (float)h[5]);
            h[6] = (f16)v1.z; l[6] = (f16)(v1.z - (float)h[6]);
            h[7] = (f16)v1.w; l[7] = (f16)(v1.w - (float)h[7]);
            xhr[i][kc] = h; xlr[i][kc] = l;
        }
    }
    __syncthreads();   // buf0 staged (barrier drains vmcnt)

    float bestv[2][4];
    int bestc[2][4];
    #pragma unroll
    for (int i = 0; i < 2; ++i)
        #pragma unroll
        for (int r = 0; r < 4; ++r) { bestv[i][r] = 3.4e38f; bestc[i][r] = 0; }

    for (int ct = 0; ct < 8; ++ct) {
        int c0 = (cs * 8 + ct) * 128;
        f32x4 acc[2][4];
        #pragma unroll
        for (int i = 0; i < 2; ++i)
            #pragma unroll
            for (int j = 0; j < 4; ++j) acc[i][j] = (f32x4)0.0f;

        #pragma unroll
        for (int kh = 0; kh < 2; ++kh) {
            // stage next phase into buf kh^1 (issue BEFORE compute)
            if (kh == 0 || ct < 7) {
                int ct1 = (kh == 0) ? ct : ct + 1;
                int kh1 = kh ^ 1;
                int c01 = (cs * 8 + ct1) * 128;
                char* dst = smem + (kh ^ 1) * 65536;
                #pragma unroll
                for (int q = 0; q < 8; ++q) {
                    int cb = q * 8 + wid;
                    int row = (cb * 4 + (lane >> 4)) & 127;
                    int ks = (((lane & 15) ^ (row & 7)) * 8) + kh1 * 128;
                    const f16* src = (cb >> 5) ? el : eh;
                    gload16(src + (size_t)(c01 + row) * D + ks, dst + cb * 1024);
                }
            }
            // compute phase (ct, kh) on buf kh
            const f16* EB = (const f16*)(smem + kh * 65536);
            #pragma unroll
            for (int kq = 0; kq < 4; ++kq) {
                f16x8 bh[4], bl[4];
                #pragma unroll
                for (int j = 0; j < 4; ++j) {
                    int brow = wc * 64 + j * 16 + (lane & 15);
                    int sw = (kq * 4 + (lane >> 4)) ^ rxor;
                    bh[j] = *(const f16x8*)(EB + brow * 128 + sw * 8);
                    bl[j] = *(const f16x8*)(EB + 16384 + brow * 128 + sw * 8);
                }
                #pragma unroll
                for (int i = 0; i < 2; ++i)
                    #pragma unroll
                    for (int j = 0; j < 4; ++j)
                        acc[i][j] = MFMA16(xhr[i][kh * 4 + kq], bh[j], acc[i][j]);
                #pragma unroll
                for (int i = 0; i < 2; ++i)
                    #pragma unroll
                    for (int j = 0; j < 4; ++j)
                        acc[i][j] = MFMA16(xhr[i][kh * 4 + kq], bl[j], acc[i][j]);
                #pragma unroll
                for (int i = 0; i < 2; ++i)
                    #pragma unroll
                    for (int j = 0; j < 4; ++j)
                        acc[i][j] = MFMA16(xlr[i][kh * 4 + kq], bh[j], acc[i][j]);
            }
            __syncthreads();   // staged buf ready; current buf released
        }
        // score = ||e||^2 - 2 x.e ; cols ascend with (ct, j) -> strict < keeps first
        float enj[4];
        #pragma unroll
        for (int j = 0; j < 4; ++j) enj[j] = enorm[c0 + wc * 64 + j * 16 + (lane & 15)];
        #pragma unroll
        for (int i = 0; i < 2; ++i)
            #pragma unroll
            for (int j = 0; j < 4; ++j) {
                int c = c0 + wc * 64 + j * 16 + (lane & 15);
                #pragma unroll
                for (int r = 0; r < 4; ++r) {
                    float s = enj[j] - 2.0f * acc[i][j][r];
                    if (s < bestv[i][r]) { bestv[i][r] = s; bestc[i][r] = c; }
                }
            }
    }

    // reduce across the 16 lanes (lane&15) holding the same rows
    float rv[2][4]; int rc[2][4];
    #pragma unroll
    for (int i = 0; i < 2; ++i)
        #pragma unroll
        for (int r = 0; r < 4; ++r) {
            float v = bestv[i][r]; int c = bestc[i][r];
            #pragma unroll
            for (int off = 8; off; off >>= 1) {
                float ov = __shfl_xor(v, off);
                int oc = __shfl_xor(c, off);
                if (ov < v || (ov == v && oc < c)) { v = ov; c = oc; }
            }
            rv[i][r] = v; rc[i][r] = c;
            if ((lane & 15) == 0 && wc == 1) {
                int rloc = i * 16 + (lane >> 4) * 4 + r;
                float2 p; p.x = v; p.y = __int_as_float(c);
                msm[wr][rloc] = p;   // LDS dead after final phase barrier
            }
        }
    __syncthreads();
    if (wc == 0 && (lane & 15) == 0) {
        #pragma unroll
        for (int i = 0; i < 2; ++i)
            #pragma unroll
            for (int r = 0; r < 4; ++r) {
                int rloc = i * 16 + (lane >> 4) * 4 + r;
                float v = rv[i][r]; int c = rc[i][r];
                float2 o = msm[wr][rloc];
                float ov = o.x; int oc = __float_as_int(o.y);
                if (ov < v || (ov == v && oc < c)) { v = ov; c = oc; }
                float2 p; p.x = v; p.y = __int_as_float(c);
                cand[(size_t)cs * N + row0 + wr * 32 + rloc] = p;
            }
    }
}

// ---------------- fused: merge 4 candidates + gather + ST + loss ----------------
__global__ __launch_bounds__(256) void gather_merge(
    const float* __restrict__ x, const float* __restrict__ emb,
    const float2* __restrict__ cand, float* __restrict__ out,
    float* __restrict__ idx_f, unsigned* __restrict__ counts,
    float* __restrict__ lpart, float* __restrict__ npart)
{
    int tid = threadIdx.x, lane = tid & 63, wid = tid >> 6;
    __shared__ float ls[4], ns[4];
    double lacc = 0.0, nacc = 0.0;
    for (int it = 0; it < 4; ++it) {
        int row = (blockIdx.x * 4 + wid) + it * (C_BLOCKS * 4);
        // merge 4 col-split candidates (all lanes, broadcast loads)
        float bv = 3.4e38f; int bc = 0;
        #pragma unroll
        for (int cs = 0; cs < 4; ++cs) {
            float2 p = cand[(size_t)cs * N + row];
            int cc = __float_as_int(p.y);
            if (p.x < bv || (p.x == bv && cc < bc)) { bv = p.x; bc = cc; }
        }
        if (lane == 0) {
            idx_f[row] = (float)bc;
            atomicAdd(&counts[bc], 1u);
        }
        int c = bc;
        float4 xv = *(const float4*)(x + (size_t)row * D + lane * 4);
        float4 qv = *(const float4*)(emb + (size_t)c * D + lane * 4);
        float4 o;   // mimic x + (q - x) rounding
        o.x = xv.x + (qv.x - xv.x); o.y = xv.y + (qv.y - xv.y);
        o.z = xv.z + (qv.z - xv.z); o.w = xv.w + (qv.w - xv.w);
        *(float4*)(out + (size_t)row * D + lane * 4) = o;
        float dx = xv.x - qv.x, dy = xv.y - qv.y, dz = xv.z - qv.z, dw = xv.w - qv.w;
        float ss = dx * dx + dy * dy + dz * dz + dw * dw;
        float sa = fabsf(xv.x) + fabsf(xv.y) + fabsf(xv.z) + fabsf(xv.w);
        #pragma unroll
        for (int off = 32; off; off >>= 1) {
            ss += __shfl_xor(ss, off);
            sa += __shfl_xor(sa, off);
        }
        if (sa > 0.0f) { lacc += (double)ss * (1.0 / 256.0); nacc += 1.0; }
    }
    if (lane == 0) { ls[wid] = (float)lacc; ns[wid] = (float)nacc; }
    __syncthreads();
    if (tid == 0) {
        lpart[blockIdx.x] = ls[0] + ls[1] + ls[2] + ls[3];
        npart[blockIdx.x] = ns[0] + ns[1] + ns[2] + ns[3];
    }
}

// ---------------- fp32 fallback argmin (round-2 proven) ----------------
#define BR 64
#define BC 128
#define BK 64
__global__ __launch_bounds__(256) void argmin_fp32(
    const float* __restrict__ x, const float* __restrict__ emb,
    const float* __restrict__ enorm, unsigned* __restrict__ counts,
    int* __restrict__ idx_out, float* __restrict__ idx_f)
{
    __shared__ float xs[BR][65];
    __shared__ float es[BC][65];
    __shared__ float en_s[BC];
    int tid = threadIdx.x;
    int ty = tid >> 4, tx = tid & 15;
    int r0 = blockIdx.x * BR;
    float bestv[4]; int bestc[4];
    #pragma unroll
    for (int i = 0; i < 4; ++i) { bestv[i] = 3.4e38f; bestc[i] = 0; }
    for (int ct = 0; ct < M / BC; ++ct) {
        int c0 = ct * BC;
        float acc[4][8];
        #pragma unroll
        for (int i = 0; i < 4; ++i)
            #pragma unroll
            for (int j = 0; j < 8; ++j) acc[i][j] = 0.0f;
        for (int kt = 0; kt < D / BK; ++kt) {
            __syncthreads();
            #pragma unroll
            for (int p = 0; p < 4; ++p) {
                int l = p * 256 + tid, r = l >> 4, k4 = l & 15;
                float4 v = *(const float4*)(x + (size_t)(r0 + r) * D + kt * BK + k4 * 4);
                xs[r][k4 * 4] = v.x; xs[r][k4 * 4 + 1] = v.y;
                xs[r][k4 * 4 + 2] = v.z; xs[r][k4 * 4 + 3] = v.w;
            }
            #pragma unroll
            for (int p = 0; p < 8; ++p) {
                int l = p * 256 + tid, r = l >> 4, k4 = l & 15;
                float4 v = *(const float4*)(emb + (size_t)(c0 + r) * D + kt * BK + k4 * 4);
                es[r][k4 * 4] = v.x; es[r][k4 * 4 + 1] = v.y;
                es[r][k4 * 4 + 2] = v.z; es[r][k4 * 4 + 3] = v.w;
            }
            if (kt == 0 && tid < BC) en_s[tid] = enorm[c0 + tid];
            __syncthreads();
            #pragma unroll 8
            for (int k = 0; k < BK; ++k) {
                float xv[4], ev[8];
                #pragma unroll
                for (int i = 0; i < 4; ++i) xv[i] = xs[ty + 16 * i][k];
                #pragma unroll
                for (int j = 0; j < 8; ++j) ev[j] = es[tx + 16 * j][k];
                #pragma unroll
                for (int i = 0; i < 4; ++i)
                    #pragma unroll
                    for (int j = 0; j < 8; ++j)
                        acc[i][j] = fmaf(xv[i], ev[j], acc[i][j]);
            }
        }
        #pragma unroll
        for (int i = 0; i < 4; ++i)
            #pragma unroll
            for (int j = 0; j < 8; ++j) {
                int c = c0 + tx + 16 * j;
                float s = en_s[tx + 16 * j] - 2.0f * acc[i][j];
                if (s < bestv[i]) { bestv[i] = s; bestc[i] = c; }
            }
    }
    #pragma unroll
    for (int i = 0; i < 4; ++i) {
        float v = bestv[i]; int c = bestc[i];
        #pragma unroll
        for (int off = 8; off; off >>= 1) {
            float ov = __shfl_xor(v, off, 16);
            int oc = __shfl_xor(c, off, 16);
            if (ov < v || (ov == v && oc < c)) { v = ov; c = oc; }
        }
        if (tx == 0) {
            int row = r0 + ty + 16 * i;
            idx_out[row] = c; idx_f[row] = (float)c;
            atomicAdd(&counts[c], 1u);
        }
    }
}

// ---------------- fallback gather (reads idx) ----------------
__global__ __launch_bounds__(256) void gather_kernel(
    const float* __restrict__ x, const float* __restrict__ emb,
    const int* __restrict__ idx, float* __restrict__ out,
    float* __restrict__ lpart, float* __restrict__ npart)
{
    int tid = threadIdx.x, lane = tid & 63, wid = tid >> 6;
    __shared__ float ls[4], ns[4];
    double lacc = 0.0, nacc = 0.0;
    for (int it = 0; it < 4; ++it) {
        int row = (blockIdx.x * 4 + wid) + it * (C_BLOCKS * 4);
        int c = idx[row];
        float4 xv = *(const float4*)(x + (size_t)row * D + lane * 4);
        float4 qv = *(const float4*)(emb + (size_t)c * D + lane * 4);
        float4 o;
        o.x = xv.x + (qv.x - xv.x); o.y = xv.y + (qv.y - xv.y);
        o.z = xv.z + (qv.z - xv.z); o.w = xv.w + (qv.w - xv.w);
        *(float4*)(out + (size_t)row * D + lane * 4) = o;
        float dx = xv.x - qv.x, dy = xv.y - qv.y, dz = xv.z - qv.z, dw = xv.w - qv.w;
        float ss = dx * dx + dy * dy + dz * dz + dw * dw;
        float sa = fabsf(xv.x) + fabsf(xv.y) + fabsf(xv.z) + fabsf(xv.w);
        #pragma unroll
        for (int off = 32; off; off >>= 1) {
            ss += __shfl_xor(ss, off);
            sa += __shfl_xor(sa, off);
        }
        if (sa > 0.0f) { lacc += (double)ss * (1.0 / 256.0); nacc += 1.0; }
    }
    if (lane == 0) { ls[wid] = (float)lacc; ns[wid] = (float)nacc; }
    __syncthreads();
    if (tid == 0) {
        lpart[blockIdx.x] = ls[0] + ls[1] + ls[2] + ls[3];
        npart[blockIdx.x] = ns[0] + ns[1] + ns[2] + ns[3];
    }
}

// ---------------- K4: perplexity + loss finalize ----------------
__global__ __launch_bounds__(256) void finalize_kernel(
    const unsigned* __restrict__ counts, const float* __restrict__ lpart,
    const float* __restrict__ npart, float* __restrict__ out)
{
    __shared__ double sd[256];
    __shared__ double sl[256];
    __shared__ double sn[256];
    int tid = threadIdx.x;
    double t = 0.0;
    for (int i = tid; i < M; i += 256) {
        double p = (double)counts[i] * (1.0 / 32768.0);
        t += p * log(p + 1e-10);
    }
    sd[tid] = t;
    double ln = 0.0, nn = 0.0;
    for (int i = tid; i < C_BLOCKS; i += 256) { ln += lpart[i]; nn += npart[i]; }
    sl[tid] = ln; sn[tid] = nn;
    __syncthreads();
    for (int s = 128; s; s >>= 1) {
        if (tid < s) { sd[tid] += sd[tid + s]; sl[tid] += sl[tid + s]; sn[tid] += sn[tid + s]; }
        __syncthreads();
    }
    if (tid == 0) {
        out[PERP_OFF] = (float)exp(-sd[0]);
        out[LOSS_OFF] = (float)(0.25 * sl[0] / sn[0]);
    }
}

extern "C" void kernel_launch(void* const* d_in, const int* in_sizes, int n_in,
                              void* d_out, int out_size, void* d_ws, size_t ws_size,
                              hipStream_t stream) {
    const float* x = (const float*)d_in[0];
    const float* emb = (const float*)d_in[1];
    float* out = (float*)d_out;
    char* ws = (char*)d_ws;

    float* enorm = (float*)(ws + WS_ENORM);
    unsigned* counts = (unsigned*)(ws + WS_COUNTS);
    float* lpart = (float*)(ws + WS_LPART);
    float* npart = (float*)(ws + WS_NPART);

    if (ws_size >= (size_t)WS_NEEDED) {
        f16* eh = (f16*)(ws + WS_EH);
        f16* el = (f16*)(ws + WS_EL);
        float2* cand = (float2*)(ws + WS_CAND);

        init_kernel<<<M / 4, 256, 0, stream>>>(emb, enorm, counts);
        convert_kernel<<<(M * D / 4) / 256, 256, 0, stream>>>(emb, eh, el, M * D / 4);
        argmin_xr<<<1024, 512, 131072, stream>>>(x, eh, el, enorm, cand);
        gather_merge<<<C_BLOCKS, 256, 0, stream>>>(x, emb, cand, out, out + IDX_OFF,
                                                   counts, lpart, npart);
    } else {
        // fallback: small-ws layout (round-2 proven)
        enorm = (float*)(ws + 0);
        counts = (unsigned*)(ws + 16384);
        int* idx = (int*)(ws + 32768);
        lpart = (float*)(ws + 163840);
        npart = (float*)(ws + 172032);
        init_kernel<<<M / 4, 256, 0, stream>>>(emb, enorm, counts);
        argmin_fp32<<<N / BR, 256, 0, stream>>>(x, emb, enorm, counts, idx, out + IDX_OFF);
        gather_kernel<<<C_BLOCKS, 256, 0, stream>>>(x, emb, idx, out, lpart, npart);
    }
    finalize_kernel<<<1, 256, 0, stream>>>(counts, lpart, npart, out);
}